// Round 3
// baseline (238.560 us; speedup 1.0000x reference)
//
#include <hip/hip_runtime.h>

typedef _Float16 half8 __attribute__((ext_vector_type(8)));
typedef _Float16 half4v __attribute__((ext_vector_type(4)));
typedef _Float16 half2v __attribute__((ext_vector_type(2)));
typedef float f32x4 __attribute__((ext_vector_type(4)));

// async 16B global->LDS copy (HW: LDS dest = wave-uniform base + lane*16)
#define ASYNC_CP16(gp, lp)                                       \
  __builtin_amdgcn_global_load_lds(                              \
      (const __attribute__((address_space(1))) void*)(gp),       \
      (__attribute__((address_space(3))) void*)(lp), 16, 0, 0)

static __device__ __forceinline__ half8 mulw(half8 a, half8 s) {
  half8 o;
#pragma unroll
  for (int j = 0; j < 8; j++) o[j] = a[j] * s[j];  // v_pk_mul_f16 x4
  return o;
}

// ---------------------------------------------------------------------------
// Convert Wq||Wk||Wv (fp32 [O,512] each) -> Wb fp16 [1024][512] (c-inner)
// ---------------------------------------------------------------------------
__global__ __launch_bounds__(256) void conv_w(const float* __restrict__ Wq,
                                              const float* __restrict__ Wk,
                                              const float* __restrict__ Wv,
                                              _Float16* __restrict__ Wb) {
  int idx = blockIdx.x * 256 + threadIdx.x;  // 0 .. 1024*512
  int row = idx >> 9;
  float v;
  if (row < 256)      v = Wq[idx];
  else if (row < 512) v = Wk[idx - 256 * 512];
  else                v = Wv[idx - 512 * 512];
  Wb[idx] = (_Float16)v;
}

// ---------------------------------------------------------------------------
// x fp32 [B][512][2048] -> xT fp16 [B][2048][512]   (LDS-tiled transpose)
// ---------------------------------------------------------------------------
__global__ __launch_bounds__(256) void conv_xT(const float* __restrict__ x,
                                               _Float16* __restrict__ xT) {
  __shared__ float T[32][33];
  const int b = blockIdx.z;
  const int n0 = blockIdx.x * 32, c0 = blockIdx.y * 32;
  const int t = threadIdx.x;
  const float* xb = x + (size_t)b * 512 * 2048;
  const int n2 = t & 15, cr = t >> 4;  // load: 16 float2-cols x 16 c-rows
#pragma unroll
  for (int r = 0; r < 2; r++) {
    int c = cr + r * 16;
    float2 v = *(const float2*)&xb[(size_t)(c0 + c) * 2048 + n0 + n2 * 2];
    T[c][n2 * 2] = v.x;
    T[c][n2 * 2 + 1] = v.y;
  }
  __syncthreads();
  _Float16* xtb = xT + (size_t)b * 2048 * 512;
  const int c2 = t & 15, nr = t >> 4;  // store: 16 half2-cols x 16 n-rows
#pragma unroll
  for (int r = 0; r < 2; r++) {
    int n = nr + r * 16;
    half2v h;
    h[0] = (_Float16)T[c2 * 2][n];
    h[1] = (_Float16)T[c2 * 2 + 1][n];
    *(half2v*)&xtb[(size_t)(n0 + n) * 512 + c0 + c2 * 2] = h;
  }
}

// ---------------------------------------------------------------------------
// NT-GEMM (proj + sim): C[m][n] = sum_k A[m][k]*B[n][k], fp16 in.
// Block 256 thr = 4 waves; block tile 128x128; wave tile 64x64 (4x4 MFMAs).
// BUFS-buffered async staging (global_load_lds w=16), prefetch dist BUFS-1,
// raw-asm barrier (vmcnt(4) mid-loop for BUFS=3; in-order vmcnt retire).
// XOR swizzle on the GLOBAL source side keeps frag ds_read_b128 conflict-free:
//   LDS slot (row r, 16B-chunk c') holds global chunk c' ^ ((r>>1)&3).
// MODE 1 (PROJ3): m_blk<512 -> transposed fp16 store into C (qkT); else
//   natural fp16 store into C2 (v) at row m-512.
// MODE 2 (SIM): store h = fp16(exp(logit - mx)) where mx is the PER-WAVE
//   column max over its 64 m's; emit partials pm=mx, ps=sum(rounded h) at
//   64-row granularity: pm/ps[b][32][2048].  (no cross-wave merge needed)
// ---------------------------------------------------------------------------
template <typename OutT, int BUFS, int MODE>
__global__ __launch_bounds__(256) void gemm_nt(
    const _Float16* __restrict__ A, const _Float16* __restrict__ B,
    OutT* __restrict__ C, OutT* __restrict__ C2, int K, int lda, int ldb,
    int ldc, int ldc2, long sA, long sB, long sC, float* __restrict__ pm,
    float* __restrict__ ps) {
  A += (size_t)blockIdx.z * sA;
  B += (size_t)blockIdx.z * sB;
  C += (size_t)blockIdx.z * sC;
  if constexpr (MODE == 1) C2 += (size_t)blockIdx.z * sC;
  const int m_blk = blockIdx.y * 128, n_blk = blockIdx.x * 128;

  __shared__ _Float16 As[BUFS][4096];  // [buf][128 rows][32 k halves]
  __shared__ _Float16 Bs[BUFS][4096];

  const int t = threadIdx.x;
  const int lane = t & 63, wave = t >> 6;
  const int quad = lane >> 4, l16 = lane & 15;
  const int wm = (wave & 1) * 64, wn = (wave >> 1) * 64;

  const int srow = 16 * wave + (lane >> 2);
  const int schunk = (lane & 3) ^ ((lane >> 3) & 3);  // XOR swizzle
  const _Float16* gA0 = A + (size_t)(m_blk + srow) * lda + schunk * 8;
  const _Float16* gA1 = gA0 + (size_t)64 * lda;
  const _Float16* gB0 = B + (size_t)(n_blk + srow) * ldb + schunk * 8;
  const _Float16* gB1 = gB0 + (size_t)64 * ldb;
  const int lofs = wave * 512 + lane * 8;  // halves within one buffer

  const int rchunk = (quad ^ ((l16 >> 1) & 3)) * 8;

  f32x4 acc[4][4] = {};

#pragma unroll
  for (int pb = 0; pb < BUFS - 1; pb++) {
    if (pb * 32 < K) {
      ASYNC_CP16(gA0 + pb * 32, &As[pb][lofs]);
      ASYNC_CP16(gA1 + pb * 32, &As[pb][lofs + 2048]);
      ASYNC_CP16(gB0 + pb * 32, &Bs[pb][lofs]);
      ASYNC_CP16(gB1 + pb * 32, &Bs[pb][lofs + 2048]);
    }
  }

  int ib = 0;
  for (int k0 = 0; k0 < K; k0 += 32) {
    if constexpr (BUFS == 3) {
      if (k0 + 32 < K)
        asm volatile("s_waitcnt vmcnt(4)\n\ts_barrier" ::: "memory");
      else
        asm volatile("s_waitcnt vmcnt(0)\n\ts_barrier" ::: "memory");
    } else {
      asm volatile("s_waitcnt vmcnt(0)\n\ts_barrier" ::: "memory");
    }
    if (k0 + (BUFS - 1) * 32 < K) {
      int nb = ib + BUFS - 1;
      if (nb >= BUFS) nb -= BUFS;
      const int ko = k0 + (BUFS - 1) * 32;
      ASYNC_CP16(gA0 + ko, &As[nb][lofs]);
      ASYNC_CP16(gA1 + ko, &As[nb][lofs + 2048]);
      ASYNC_CP16(gB0 + ko, &Bs[nb][lofs]);
      ASYNC_CP16(gB1 + ko, &Bs[nb][lofs + 2048]);
    }
    half8 af[4], bf[4];
#pragma unroll
    for (int i = 0; i < 4; i++) {
      af[i] = *(const half8*)&As[ib][(wm + i * 16 + l16) * 32 + rchunk];
      bf[i] = *(const half8*)&Bs[ib][(wn + i * 16 + l16) * 32 + rchunk];
    }
#pragma unroll
    for (int i = 0; i < 4; i++)
#pragma unroll
      for (int j = 0; j < 4; j++)
        acc[i][j] =
            __builtin_amdgcn_mfma_f32_16x16x32_f16(af[i], bf[j], acc[i][j], 0, 0, 0);
    ib++;
    if (ib == BUFS) ib = 0;
  }

  if constexpr (MODE == 2) {
    // per-wave-column softmax partials + exp-store (D row = quad*4+reg,
    // col = l16 in each 16x16 tile; wave column has 64 m's across i,quad,r)
#pragma unroll
    for (int j = 0; j < 4; j++) {
      const int n0 = n_blk + wn + j * 16 + l16;
      float mx = acc[0][j][0];
#pragma unroll
      for (int i = 0; i < 4; i++)
#pragma unroll
        for (int r = 0; r < 4; r++) mx = fmaxf(mx, acc[i][j][r]);
      mx = fmaxf(mx, __shfl_xor(mx, 16, 64));
      mx = fmaxf(mx, __shfl_xor(mx, 32, 64));
      float es = 0.f;
#pragma unroll
      for (int i = 0; i < 4; i++) {
        const int m0 = m_blk + wm + i * 16 + quad * 4;
#pragma unroll
        for (int r = 0; r < 4; r++) {
          _Float16 h = (_Float16)__expf(acc[i][j][r] - mx);
          C[(size_t)(m0 + r) * ldc + n0] = h;
          es += (float)h;
        }
      }
      es += __shfl_xor(es, 16, 64);
      es += __shfl_xor(es, 32, 64);
      if (quad == 0) {
        size_t o =
            ((size_t)blockIdx.z * 32 + blockIdx.y * 2 + (wave & 1)) * 2048 + n0;
        pm[o] = mx;
        ps[o] = es;
      }
    }
  } else {
#pragma unroll
    for (int i = 0; i < 4; i++) {
      const int m0 = m_blk + wm + i * 16 + quad * 4;
#pragma unroll
      for (int j = 0; j < 4; j++) {
        const int n0 = n_blk + wn + j * 16 + l16;
        if constexpr (MODE == 1) {
          if (m_blk < 512) {  // q|k rows: transposed store into qkT
            half4v h;
#pragma unroll
            for (int r = 0; r < 4; r++) h[r] = (_Float16)acc[i][j][r];
            *(half4v*)&C[(size_t)n0 * ldc + m0] = h;
          } else {  // v rows: natural store v[(m-512)][n]
#pragma unroll
            for (int r = 0; r < 4; r++)
              C2[(size_t)(m0 - 512 + r) * ldc2 + n0] = (OutT)acc[i][j][r];
          }
        } else {
#pragma unroll
          for (int r = 0; r < 4; r++)
            C[(size_t)(m0 + r) * ldc + n0] = (OutT)acc[i][j][r];
        }
      }
    }
  }
}

// ---------------------------------------------------------------------------
// Merge 32 per-64-row partials per column -> fp16 scale[b][32][2048]:
// scale[i][col] = exp(pm_i - M) / S,  S = sum_i ps_i * exp(pm_i - M).
// attn[m,k] = h[m,k] * scale[m>>6, k]; normalization exact by construction.
// Grid (nb*2048/256).
// ---------------------------------------------------------------------------
__global__ __launch_bounds__(256) void colstats2(const float* __restrict__ pm,
                                                 const float* __restrict__ ps,
                                                 _Float16* __restrict__ scl) {
  const int idx = blockIdx.x * 256 + threadIdx.x;  // b*2048 + col
  const int b = idx >> 11, col = idx & 2047;
  const float* pmb = pm + (size_t)b * 32 * 2048 + col;
  const float* psb = ps + (size_t)b * 32 * 2048 + col;
  float pv[32];
  float m = -3.0e38f;
#pragma unroll
  for (int i = 0; i < 32; i++) {
    pv[i] = pmb[(size_t)i * 2048];
    m = fmaxf(m, pv[i]);
  }
  float s = 0.f;
#pragma unroll
  for (int i = 0; i < 32; i++) {
    pv[i] = __expf(pv[i] - m);
    s += psb[(size_t)i * 2048] * pv[i];
  }
  const float inv = 1.0f / s;
  _Float16* so = scl + (size_t)b * 32 * 2048 + col;
#pragma unroll
  for (int i = 0; i < 32; i++) so[(size_t)i * 2048] = (_Float16)(pv[i] * inv);
}

// ---------------------------------------------------------------------------
// Stage-D: out[m][c] = sum_k (P[m][k]*scale[m>>6,k]) * V[c][k].
// P fp16 [2048][2048] (unnorm. exp), V fp16 [512][2048], scale fp16 [32][2048]
// per batch, out fp32 [2048][512].
// ROUND-3 RESTRUCTURE: barrier-free wave-private pipeline.
//   Evidence: round-0 iter-round time (2400cyc) ~= MFMA(620)+VALU(380)+
//   LDS(1130) SUMMED -> the 2-phase barrier loop serializes the pipes.
//   Round-1 (occupancy 2x) and round-2 (A off LDS via global gather) both
//   failed to move MfmaUtil -> attack the serialization itself.
// Block 256 = 4 waves, tile 128x128, wave tile 64x64 (4x4 MFMAs), but the
// waves are fully INDEPENDENT: no __syncthreads / asm barriers in the loop.
//  - A (P rows) + scale: wave stages only ITS 64 rows into a PRIVATE LDS
//    double-buffer (4KB/buf): coalesced 16-rowx64B loads, ONE scale chunk
//    (the wave's 64 rows = one scale group), 4x mulw, 4x ds_write_b128.
//    In-wave write->read needs no barrier (in-order DS pipe + compiler
//    lgkmcnt).  XOR swizzle sigma(row)=(row>>1)&3 on the k-chunk keeps the
//    frag ds_read_b128 conflict-free (slot c holds data chunk c^sigma).
//  - B (V rows): direct global->reg MFMA fragments (row=wn+j*16+l16,
//    k=quad*8) - V is 2MB/batch, L2-resident per XCD (batch=XCD swizzle),
//    no swizzle needed, kills Bs LDS traffic (24KB/iter/block) + all cp16
//    vmcnt bookkeeping.
//  - Prefetch dist 1 tile for both A-regs and B-regs (named rotation).
// LDS 32KB/block; LDS/iter/block = 8KB writes... reads 16KB (was 48KB).
// Expected: pipes overlap across the 2 free-running waves/SIMD.
// ---------------------------------------------------------------------------
__global__ __launch_bounds__(256, 2) void gemm_av(
    const _Float16* __restrict__ P, const _Float16* __restrict__ V,
    const _Float16* __restrict__ scl, float* __restrict__ C, int cbatch) {
  int lin = blockIdx.x, z, idx;
  if (cbatch == 8) {
    z = lin & 7;
    idx = lin >> 3;
  } else {
    z = lin >> 6;
    idx = lin & 63;
  }
  const int n_blk = (idx & 3) * 128;   // c-dim
  const int m_blk = (idx >> 2) * 128;  // m-dim
  P += (size_t)z * 2048 * 2048;
  V += (size_t)z * 512 * 2048;
  scl += (size_t)z * 32 * 2048;
  C += (size_t)z * 2048 * 512;

  __shared__ _Float16 As[4][2][2048];  // [wave][buf][64 rows][32 halves] 32KB

  const int t = threadIdx.x;
  const int lane = t & 63, wave = t >> 6;
  const int quad = lane >> 4, l16 = lane & 15;
  const int wm = (wave & 1) * 64, wn = (wave >> 1) * 64;

  // A staging: lane stages rows {c*16 + (lane>>2)} (c=0..3) at k-chunk kc,
  // slot chunk = lane&3; data chunk kc = (lane&3) ^ sigma(row), sigma=(l>>3)&3
  const int kc = (lane & 3) ^ ((lane >> 3) & 3);
  const _Float16* gA = P + (size_t)(m_blk + wm + (lane >> 2)) * 2048 + kc * 8;
  const _Float16* gS =
      scl + (size_t)((m_blk + wm) >> 6) * 2048 + kc * 8;  // single group/wave
  // B direct-frag: row = n_blk + wn + j*16 + l16, k = k0 + quad*8
  const _Float16* gB = V + (size_t)(n_blk + wn + l16) * 2048 + quad * 8;

  const int sofs = lane * 8;  // = (lane>>2)*32 + (lane&3)*8
  const int rchunk = (quad ^ ((l16 >> 1) & 3)) * 8;
  _Float16* myA = &As[wave][0][0];

  f32x4 acc[4][4] = {};

  // prologue: tile 0 -> regs -> staged; B tile 0 -> regs
  {
    half8 a0 = *(const half8*)(gA);
    half8 a1 = *(const half8*)(gA + 16 * 2048);
    half8 a2 = *(const half8*)(gA + 32 * 2048);
    half8 a3 = *(const half8*)(gA + 48 * 2048);
    half8 s0 = *(const half8*)(gS);
    *(half8*)&myA[sofs] = mulw(a0, s0);
    *(half8*)&myA[sofs + 512] = mulw(a1, s0);
    *(half8*)&myA[sofs + 1024] = mulw(a2, s0);
    *(half8*)&myA[sofs + 1536] = mulw(a3, s0);
  }
  half8 b0 = *(const half8*)(gB);
  half8 b1 = *(const half8*)(gB + 16 * 2048);
  half8 b2 = *(const half8*)(gB + 32 * 2048);
  half8 b3 = *(const half8*)(gB + 48 * 2048);

  int p = 0;
  for (int k0 = 0; k0 < 2048; k0 += 32) {
    const bool more = (k0 + 32 < 2048);
    // prefetch tile k+1: A+scale and B fragments into regs (issued early)
    half8 na0, na1, na2, na3, ns0, nb0, nb1, nb2, nb3;
    if (more) {
      na0 = *(const half8*)(gA + k0 + 32);
      na1 = *(const half8*)(gA + 16 * 2048 + k0 + 32);
      na2 = *(const half8*)(gA + 32 * 2048 + k0 + 32);
      na3 = *(const half8*)(gA + 48 * 2048 + k0 + 32);
      ns0 = *(const half8*)(gS + k0 + 32);
      nb0 = *(const half8*)(gB + k0 + 32);
      nb1 = *(const half8*)(gB + 16 * 2048 + k0 + 32);
      nb2 = *(const half8*)(gB + 32 * 2048 + k0 + 32);
      nb3 = *(const half8*)(gB + 48 * 2048 + k0 + 32);
    }
    // A fragments from the wave-private staged buffer
    half8 af[4];
#pragma unroll
    for (int i = 0; i < 4; i++)
      af[i] = *(const half8*)&myA[p * 2048 + i * 512 + l16 * 32 + rchunk];
    __builtin_amdgcn_s_setprio(1);
#pragma unroll
    for (int i = 0; i < 4; i++) {
      acc[i][0] = __builtin_amdgcn_mfma_f32_16x16x32_f16(af[i], b0, acc[i][0], 0, 0, 0);
      acc[i][1] = __builtin_amdgcn_mfma_f32_16x16x32_f16(af[i], b1, acc[i][1], 0, 0, 0);
      acc[i][2] = __builtin_amdgcn_mfma_f32_16x16x32_f16(af[i], b2, acc[i][2], 0, 0, 0);
      acc[i][3] = __builtin_amdgcn_mfma_f32_16x16x32_f16(af[i], b3, acc[i][3], 0, 0, 0);
    }
    __builtin_amdgcn_s_setprio(0);
    if (more) {  // stage tile k+1 into the other private buffer; rotate B
      _Float16* dst = &myA[(p ^ 1) * 2048];
      *(half8*)&dst[sofs] = mulw(na0, ns0);
      *(half8*)&dst[sofs + 512] = mulw(na1, ns0);
      *(half8*)&dst[sofs + 1024] = mulw(na2, ns0);
      *(half8*)&dst[sofs + 1536] = mulw(na3, ns0);
      b0 = nb0;
      b1 = nb1;
      b2 = nb2;
      b3 = nb3;
    }
    p ^= 1;
  }

  // epilogue: natural fp32 store C[m][c]
#pragma unroll
  for (int i = 0; i < 4; i++) {
    const int m0 = m_blk + wm + i * 16 + quad * 4;
#pragma unroll
    for (int j = 0; j < 4; j++) {
      const int n0 = n_blk + wn + j * 16 + l16;
#pragma unroll
      for (int r = 0; r < 4; r++) C[(size_t)(m0 + r) * 512 + n0] = acc[i][j][r];
    }
  }
}

// ---------------------------------------------------------------------------
extern "C" void kernel_launch(void* const* d_in, const int* in_sizes, int n_in,
                              void* d_out, int out_size, void* d_ws,
                              size_t ws_size, hipStream_t stream) {
  const float* x = (const float*)d_in[0];
  const float* Wq = (const float*)d_in[1];
  const float* Wk = (const float*)d_in[2];
  const float* Wv = (const float*)d_in[3];
  float* out = (float*)d_out;

  char* p = (char*)d_ws;
  auto alloc = [&](size_t bytes) -> char* {
    char* r = p;
    p += (bytes + 255) & ~(size_t)255;
    return r;
  };
  const size_t NB = 8, N = 2048, CIN = 512, CO = 512;
  _Float16* Wb = (_Float16*)alloc(1024 * 512 * sizeof(_Float16));
  _Float16* xT = (_Float16*)alloc(NB * N * CIN * sizeof(_Float16));
  _Float16* qkT = (_Float16*)alloc(NB * N * 512 * sizeof(_Float16));  // [n][q|k]
  _Float16* v = (_Float16*)alloc(NB * CO * N * sizeof(_Float16));     // [c][n]
  size_t base_used = (size_t)(p - (char*)d_ws);

  // per-batch bytes for the sim chain: fp16 P + partials + scale + slack
  const size_t per_b =
      (size_t)N * N * 2 + 2 * 32 * N * 4 + 32 * N * 2 + 8192;
  int cb = 8;
  while (cb > 1 && base_used + (size_t)cb * per_b > ws_size) cb >>= 1;
  _Float16* simH = (_Float16*)alloc((size_t)cb * N * N * 2);
  float* pm = (float*)alloc((size_t)cb * 32 * N * 4);
  float* ps = (float*)alloc((size_t)cb * 32 * N * 4);
  _Float16* scl = (_Float16*)alloc((size_t)cb * 32 * N * 2);

  // 1) weight convert + x transpose-convert
  conv_w<<<dim3(1024 * 512 / 256), 256, 0, stream>>>(Wq, Wk, Wv, Wb);
  conv_xT<<<dim3(64, 16, 8), 256, 0, stream>>>(x, xT);

  // 2) merged projections (q,k,v in one pass over xT):
  //    rows<512 -> qkT[n][o] transposed; rows>=512 -> v[c][n] natural
  gemm_nt<_Float16, 3, 1><<<dim3(16, 8, 8), 256, 0, stream>>>(
      Wb, xT, qkT, v, 512, 512, 512, 512, 2048, 0, (long)(N * CIN),
      (long)(N * 512), nullptr, nullptr);

  // 3) per-chunk: simH = fp16(exp(qT.kT^T - mx_wave)) + partials; merge ->
  //    fp16 scale; stage-D GEMM applies scale during A-staging -> out
  for (int b0 = 0; b0 < 8; b0 += cb) {
    const _Float16* qT = qkT + (size_t)b0 * N * 512;        // [m][c], lda 512
    const _Float16* kT = qkT + (size_t)b0 * N * 512 + 256;  // [k][c], ldb 512
    gemm_nt<_Float16, 2, 2><<<dim3(16, 16, cb), 256, 0, stream>>>(
        qT, kT, simH, nullptr, 256, 512, 512, 2048, 0, (long)(N * 512),
        (long)(N * 512), (long)(N * N), pm, ps);
    colstats2<<<dim3(cb * 8), 256, 0, stream>>>(pm, ps, scl);
    gemm_av<<<dim3(64 * cb), 256, 0, stream>>>(
        simH, v + (size_t)b0 * CO * N, scl, out + (size_t)b0 * N * CO, cb);
  }
}

// Round 5
// 215.825 us; speedup vs baseline: 1.1053x; 1.1053x over previous
//
#include <hip/hip_runtime.h>

typedef _Float16 half8 __attribute__((ext_vector_type(8)));
typedef _Float16 half4v __attribute__((ext_vector_type(4)));
typedef _Float16 half2v __attribute__((ext_vector_type(2)));
typedef float f32x4 __attribute__((ext_vector_type(4)));

// async 16B global->LDS copy (HW: LDS dest = wave-uniform base + lane*16)
#define ASYNC_CP16(gp, lp)                                       \
  __builtin_amdgcn_global_load_lds(                              \
      (const __attribute__((address_space(1))) void*)(gp),       \
      (__attribute__((address_space(3))) void*)(lp), 16, 0, 0)

static __device__ __forceinline__ half8 mulw(half8 a, half8 s) {
  half8 o;
#pragma unroll
  for (int j = 0; j < 8; j++) o[j] = a[j] * s[j];  // v_pk_mul_f16 x4
  return o;
}

// ---------------------------------------------------------------------------
// Convert Wq||Wk||Wv (fp32 [O,512] each) -> Wb fp16 [1024][512] (c-inner)
// ---------------------------------------------------------------------------
__global__ __launch_bounds__(256) void conv_w(const float* __restrict__ Wq,
                                              const float* __restrict__ Wk,
                                              const float* __restrict__ Wv,
                                              _Float16* __restrict__ Wb) {
  int idx = blockIdx.x * 256 + threadIdx.x;  // 0 .. 1024*512
  int row = idx >> 9;
  float v;
  if (row < 256)      v = Wq[idx];
  else if (row < 512) v = Wk[idx - 256 * 512];
  else                v = Wv[idx - 512 * 512];
  Wb[idx] = (_Float16)v;
}

// ---------------------------------------------------------------------------
// x fp32 [B][512][2048] -> xT fp16 [B][2048][512]   (LDS-tiled transpose)
// ---------------------------------------------------------------------------
__global__ __launch_bounds__(256) void conv_xT(const float* __restrict__ x,
                                               _Float16* __restrict__ xT) {
  __shared__ float T[32][33];
  const int b = blockIdx.z;
  const int n0 = blockIdx.x * 32, c0 = blockIdx.y * 32;
  const int t = threadIdx.x;
  const float* xb = x + (size_t)b * 512 * 2048;
  const int n2 = t & 15, cr = t >> 4;  // load: 16 float2-cols x 16 c-rows
#pragma unroll
  for (int r = 0; r < 2; r++) {
    int c = cr + r * 16;
    float2 v = *(const float2*)&xb[(size_t)(c0 + c) * 2048 + n0 + n2 * 2];
    T[c][n2 * 2] = v.x;
    T[c][n2 * 2 + 1] = v.y;
  }
  __syncthreads();
  _Float16* xtb = xT + (size_t)b * 2048 * 512;
  const int c2 = t & 15, nr = t >> 4;  // store: 16 half2-cols x 16 n-rows
#pragma unroll
  for (int r = 0; r < 2; r++) {
    int n = nr + r * 16;
    half2v h;
    h[0] = (_Float16)T[c2 * 2][n];
    h[1] = (_Float16)T[c2 * 2 + 1][n];
    *(half2v*)&xtb[(size_t)(n0 + n) * 512 + c0 + c2 * 2] = h;
  }
}

// ---------------------------------------------------------------------------
// NT-GEMM (proj + sim): C[m][n] = sum_k A[m][k]*B[n][k], fp16 in.
// Block 256 thr = 4 waves; block tile 128x128; wave tile 64x64 (4x4 MFMAs).
// BUFS-buffered async staging (global_load_lds w=16), prefetch dist BUFS-1,
// raw-asm barrier (vmcnt(4) mid-loop for BUFS=3; in-order vmcnt retire).
// XOR swizzle on the GLOBAL source side keeps frag ds_read_b128 conflict-free:
//   LDS slot (row r, 16B-chunk c') holds global chunk c' ^ ((r>>1)&3).
// MODE 1 (PROJ3): m_blk<512 -> transposed fp16 store into C (qkT); else
//   natural fp16 store into C2 (v) at row m-512.
// MODE 2 (SIM): store h = fp16(exp(logit - mx)) where mx is the PER-WAVE
//   column max over its 64 m's; emit partials pm=mx, ps=sum(rounded h) at
//   64-row granularity: pm/ps[b][32][2048].  (no cross-wave merge needed)
// ---------------------------------------------------------------------------
template <typename OutT, int BUFS, int MODE>
__global__ __launch_bounds__(256) void gemm_nt(
    const _Float16* __restrict__ A, const _Float16* __restrict__ B,
    OutT* __restrict__ C, OutT* __restrict__ C2, int K, int lda, int ldb,
    int ldc, int ldc2, long sA, long sB, long sC, float* __restrict__ pm,
    float* __restrict__ ps) {
  A += (size_t)blockIdx.z * sA;
  B += (size_t)blockIdx.z * sB;
  C += (size_t)blockIdx.z * sC;
  if constexpr (MODE == 1) C2 += (size_t)blockIdx.z * sC;
  const int m_blk = blockIdx.y * 128, n_blk = blockIdx.x * 128;

  __shared__ __align__(16) _Float16 As[BUFS][4096];  // [buf][128 rows][32 k]
  __shared__ __align__(16) _Float16 Bs[BUFS][4096];

  const int t = threadIdx.x;
  const int lane = t & 63, wave = t >> 6;
  const int quad = lane >> 4, l16 = lane & 15;
  const int wm = (wave & 1) * 64, wn = (wave >> 1) * 64;

  const int srow = 16 * wave + (lane >> 2);
  const int schunk = (lane & 3) ^ ((lane >> 3) & 3);  // XOR swizzle
  const _Float16* gA0 = A + (size_t)(m_blk + srow) * lda + schunk * 8;
  const _Float16* gA1 = gA0 + (size_t)64 * lda;
  const _Float16* gB0 = B + (size_t)(n_blk + srow) * ldb + schunk * 8;
  const _Float16* gB1 = gB0 + (size_t)64 * ldb;
  const int lofs = wave * 512 + lane * 8;  // halves within one buffer

  const int rchunk = (quad ^ ((l16 >> 1) & 3)) * 8;

  f32x4 acc[4][4] = {};

#pragma unroll
  for (int pb = 0; pb < BUFS - 1; pb++) {
    if (pb * 32 < K) {
      ASYNC_CP16(gA0 + pb * 32, &As[pb][lofs]);
      ASYNC_CP16(gA1 + pb * 32, &As[pb][lofs + 2048]);
      ASYNC_CP16(gB0 + pb * 32, &Bs[pb][lofs]);
      ASYNC_CP16(gB1 + pb * 32, &Bs[pb][lofs + 2048]);
    }
  }

  int ib = 0;
  for (int k0 = 0; k0 < K; k0 += 32) {
    if constexpr (BUFS == 3) {
      if (k0 + 32 < K)
        asm volatile("s_waitcnt vmcnt(4)\n\ts_barrier" ::: "memory");
      else
        asm volatile("s_waitcnt vmcnt(0)\n\ts_barrier" ::: "memory");
    } else {
      asm volatile("s_waitcnt vmcnt(0)\n\ts_barrier" ::: "memory");
    }
    if (k0 + (BUFS - 1) * 32 < K) {
      int nb = ib + BUFS - 1;
      if (nb >= BUFS) nb -= BUFS;
      const int ko = k0 + (BUFS - 1) * 32;
      ASYNC_CP16(gA0 + ko, &As[nb][lofs]);
      ASYNC_CP16(gA1 + ko, &As[nb][lofs + 2048]);
      ASYNC_CP16(gB0 + ko, &Bs[nb][lofs]);
      ASYNC_CP16(gB1 + ko, &Bs[nb][lofs + 2048]);
    }
    half8 af[4], bf[4];
#pragma unroll
    for (int i = 0; i < 4; i++) {
      af[i] = *(const half8*)&As[ib][(wm + i * 16 + l16) * 32 + rchunk];
      bf[i] = *(const half8*)&Bs[ib][(wn + i * 16 + l16) * 32 + rchunk];
    }
#pragma unroll
    for (int i = 0; i < 4; i++)
#pragma unroll
      for (int j = 0; j < 4; j++)
        acc[i][j] =
            __builtin_amdgcn_mfma_f32_16x16x32_f16(af[i], bf[j], acc[i][j], 0, 0, 0);
    ib++;
    if (ib == BUFS) ib = 0;
  }

  if constexpr (MODE == 2) {
    // per-wave-column softmax partials + exp-store (D row = quad*4+reg,
    // col = l16 in each 16x16 tile; wave column has 64 m's across i,quad,r)
#pragma unroll
    for (int j = 0; j < 4; j++) {
      const int n0 = n_blk + wn + j * 16 + l16;
      float mx = acc[0][j][0];
#pragma unroll
      for (int i = 0; i < 4; i++)
#pragma unroll
        for (int r = 0; r < 4; r++) mx = fmaxf(mx, acc[i][j][r]);
      mx = fmaxf(mx, __shfl_xor(mx, 16, 64));
      mx = fmaxf(mx, __shfl_xor(mx, 32, 64));
      float es = 0.f;
#pragma unroll
      for (int i = 0; i < 4; i++) {
        const int m0 = m_blk + wm + i * 16 + quad * 4;
#pragma unroll
        for (int r = 0; r < 4; r++) {
          _Float16 h = (_Float16)__expf(acc[i][j][r] - mx);
          C[(size_t)(m0 + r) * ldc + n0] = h;
          es += (float)h;
        }
      }
      es += __shfl_xor(es, 16, 64);
      es += __shfl_xor(es, 32, 64);
      if (quad == 0) {
        size_t o =
            ((size_t)blockIdx.z * 32 + blockIdx.y * 2 + (wave & 1)) * 2048 + n0;
        pm[o] = mx;
        ps[o] = es;
      }
    }
  } else {
#pragma unroll
    for (int i = 0; i < 4; i++) {
      const int m0 = m_blk + wm + i * 16 + quad * 4;
#pragma unroll
      for (int j = 0; j < 4; j++) {
        const int n0 = n_blk + wn + j * 16 + l16;
        if constexpr (MODE == 1) {
          if (m_blk < 512) {  // q|k rows: transposed store into qkT
            half4v h;
#pragma unroll
            for (int r = 0; r < 4; r++) h[r] = (_Float16)acc[i][j][r];
            *(half4v*)&C[(size_t)n0 * ldc + m0] = h;
          } else {  // v rows: natural store v[(m-512)][n]
#pragma unroll
            for (int r = 0; r < 4; r++)
              C2[(size_t)(m0 - 512 + r) * ldc2 + n0] = (OutT)acc[i][j][r];
          }
        } else {
#pragma unroll
          for (int r = 0; r < 4; r++)
            C[(size_t)(m0 + r) * ldc + n0] = (OutT)acc[i][j][r];
        }
      }
    }
  }
}

// ---------------------------------------------------------------------------
// Merge 32 per-64-row partials per column -> fp16 scale[b][32][2048]:
// scale[i][col] = exp(pm_i - M) / S,  S = sum_i ps_i * exp(pm_i - M).
// attn[m,k] = h[m,k] * scale[m>>6, k]; normalization exact by construction.
// Grid (nb*2048/256).
// ---------------------------------------------------------------------------
__global__ __launch_bounds__(256) void colstats2(const float* __restrict__ pm,
                                                 const float* __restrict__ ps,
                                                 _Float16* __restrict__ scl) {
  const int idx = blockIdx.x * 256 + threadIdx.x;  // b*2048 + col
  const int b = idx >> 11, col = idx & 2047;
  const float* pmb = pm + (size_t)b * 32 * 2048 + col;
  const float* psb = ps + (size_t)b * 32 * 2048 + col;
  float pv[32];
  float m = -3.0e38f;
#pragma unroll
  for (int i = 0; i < 32; i++) {
    pv[i] = pmb[(size_t)i * 2048];
    m = fmaxf(m, pv[i]);
  }
  float s = 0.f;
#pragma unroll
  for (int i = 0; i < 32; i++) {
    pv[i] = __expf(pv[i] - m);
    s += psb[(size_t)i * 2048] * pv[i];
  }
  const float inv = 1.0f / s;
  _Float16* so = scl + (size_t)b * 32 * 2048 + col;
#pragma unroll
  for (int i = 0; i < 32; i++) so[(size_t)i * 2048] = (_Float16)(pv[i] * inv);
}

// ---------------------------------------------------------------------------
// Stage-D: out[m][c] = sum_k (P[m][k]*scale[m>>6,k]) * V[c][k].
// P fp16 [2048][2048] (unnorm. exp), V fp16 [512][2048], scale fp16 [32][2048]
// per batch, out fp32 [2048][512].
// ROUND-4/5: round-0's proven schedule, retiled for cache-BW economics.
//   Evidence chain: R1 (2x occupancy, no change), R2 (A off LDS, worse),
//   R3 (barrier-free, worse) -> round-0's limiter is none of {occupancy,
//   LDS port, VALU, barriers}.  Remaining candidate: L2/LLC read volume:
//   round-0 read 512 MB/dispatch (P x4 c-blocks + V x16 m-blocks) in 64us
//   = 8 TB/s through the cache hierarchy.  R1 pushed it to ~768 MB and got
//   slightly SLOWER despite 2x occupancy - saturated-cache signature.
// Fix: block 512 thr = 8 waves (2m x 4c), tile 128m x 256c.  Nm=16, Nc=2:
//   P read 2x (16 MB) + V read 16x of 1MB panel (16 MB) = 32 MB/batch,
//   2.0x less cache traffic than round-0.  Grid 32/batch x 8 = 256 = exactly
//   1 block/CU (32/XCD under batch-per-XCD swizzle).  Wave tile stays 64x64
//   (4x4 MFMAs) - identical inner loop to round-0.
// B: 3 LDS bufs (256 rows x 32 halves = 16 KB/buf), async cp dist 2,
//   2 cp16/thread/iter (rows t>>2 and 128+(t>>2)).
// A: regs prefetch dist 2, staged via v_pk_mul_f16 + ds_write (XOR slot);
//   1 A-row/thread (row t>>2), single scale chunk (group (m_blk+row)>>6).
// Barrier: vmcnt(4) lgkmcnt(0) - per-iter vmem = 2 cp + 2 A/S; the mulw's
//   auto-wait on A/S(k+1) (issued AFTER cp(k+1); in-order vmcnt retire)
//   transitively guarantees the needed B tile landed (round-0 invariant).
// LDS 64 KB (As 2x8KB + Bs 3x16KB).
// ---------------------------------------------------------------------------
__global__ __launch_bounds__(512) void gemm_av(const _Float16* __restrict__ P,
                                               const _Float16* __restrict__ V,
                                               const _Float16* __restrict__ scl,
                                               float* __restrict__ C,
                                               int cbatch) {
  int lin = blockIdx.x, z, idx;
  if (cbatch == 8) {
    z = lin & 7;      // batch = XCD
    idx = lin >> 3;   // 0..31
  } else {
    z = lin >> 5;
    idx = lin & 31;
  }
  const int n_blk = (idx & 1) * 256;   // c-dim (2 blocks)
  const int m_blk = (idx >> 1) * 128;  // m-dim (16 blocks)
  P += (size_t)z * 2048 * 2048;
  V += (size_t)z * 512 * 2048;
  scl += (size_t)z * 32 * 2048;
  C += (size_t)z * 2048 * 512;

  __shared__ __align__(16) _Float16 As[2][4096];  // [buf][128 r][32 k] 8 KB
  __shared__ __align__(16) _Float16 Bs[3][8192];  // [buf][256 r][32 k] 16 KB

  const int t = threadIdx.x;
  const int lane = t & 63, wave = t >> 6;
  const int quad = lane >> 4, l16 = lane & 15;
  const int wm = (wave & 1) * 64, wn = (wave >> 1) * 64;

  // staging: thread t handles row srow = t>>2, swizzled k-chunk
  const int srow = t >> 2;                      // 0..127
  const int schunk = (t & 3) ^ ((t >> 3) & 3);  // XOR swizzle (sigma=(row>>1)&3)
  const _Float16* gA = P + (size_t)(m_blk + srow) * 2048 + schunk * 8;
  const _Float16* gS =
      scl + (size_t)((m_blk + srow) >> 6) * 2048 + schunk * 8;
  const _Float16* gB0 = V + (size_t)(n_blk + srow) * 2048 + schunk * 8;
  const _Float16* gB1 = gB0 + (size_t)128 * 2048;
  const int lofs = t * 8;  // 0..4088 halves
  const int rchunk = (quad ^ ((l16 >> 1) & 3)) * 8;

  f32x4 acc[4][4] = {};

  // prologue: B tiles 0,1 async; A tile 0 staged; A tile 1 in regs
  ASYNC_CP16(gB0, &Bs[0][lofs]);
  ASYNC_CP16(gB1, &Bs[0][lofs + 4096]);
  ASYNC_CP16(gB0 + 32, &Bs[1][lofs]);
  ASYNC_CP16(gB1 + 32, &Bs[1][lofs + 4096]);
  {
    half8 a0 = *(const half8*)gA;
    half8 s0 = *(const half8*)gS;
    *(half8*)&As[0][lofs] = mulw(a0, s0);
  }
  half8 an0 = *(const half8*)(gA + 32);
  half8 sn0 = *(const half8*)(gS + 32);
  asm volatile("s_waitcnt vmcnt(0)\n\ts_barrier" ::: "memory");

  int ibA = 0, ibB = 0;
  for (int k0 = 0; k0 < 2048; k0 += 32) {
    const bool m1 = (k0 + 32 < 2048), m2 = (k0 + 64 < 2048);
    if (m2) {  // B tile k+2 (issued FIRST: the A-reg waits then imply B done)
      int nb = ibB + 2;
      if (nb >= 3) nb -= 3;
      ASYNC_CP16(gB0 + k0 + 64, &Bs[nb][lofs]);
      ASYNC_CP16(gB1 + k0 + 64, &Bs[nb][lofs + 4096]);
    }
    half8 a2, s2;
    if (m2) {  // A/scale tile k+2 into regs
      a2 = *(const half8*)(gA + k0 + 64);
      s2 = *(const half8*)(gS + k0 + 64);
    }
    half8 af[4], bf[4];
#pragma unroll
    for (int i = 0; i < 4; i++) {
      af[i] = *(const half8*)&As[ibA][(wm + i * 16 + l16) * 32 + rchunk];
      bf[i] = *(const half8*)&Bs[ibB][(wn + i * 16 + l16) * 32 + rchunk];
    }
#pragma unroll
    for (int i = 0; i < 4; i++)
#pragma unroll
      for (int j = 0; j < 4; j++)
        acc[i][j] =
            __builtin_amdgcn_mfma_f32_16x16x32_f16(af[i], bf[j], acc[i][j], 0, 0, 0);
    if (m1) {  // stage A tile k+1 (regs loaded last iter)
      *(half8*)&As[ibA ^ 1][lofs] = mulw(an0, sn0);
      if (m2) {
        an0 = a2;
        sn0 = s2;
      }
      asm volatile("s_waitcnt vmcnt(4) lgkmcnt(0)\n\ts_barrier" ::: "memory");
    }
    ibA ^= 1;
    ibB++;
    if (ibB == 3) ibB = 0;
  }

  // epilogue: natural fp32 store C[m][c]
#pragma unroll
  for (int i = 0; i < 4; i++) {
    const int m0 = m_blk + wm + i * 16 + quad * 4;
#pragma unroll
    for (int j = 0; j < 4; j++) {
      const int n0 = n_blk + wn + j * 16 + l16;
#pragma unroll
      for (int r = 0; r < 4; r++) C[(size_t)(m0 + r) * 512 + n0] = acc[i][j][r];
    }
  }
}

// ---------------------------------------------------------------------------
extern "C" void kernel_launch(void* const* d_in, const int* in_sizes, int n_in,
                              void* d_out, int out_size, void* d_ws,
                              size_t ws_size, hipStream_t stream) {
  const float* x = (const float*)d_in[0];
  const float* Wq = (const float*)d_in[1];
  const float* Wk = (const float*)d_in[2];
  const float* Wv = (const float*)d_in[3];
  float* out = (float*)d_out;

  char* p = (char*)d_ws;
  auto alloc = [&](size_t bytes) -> char* {
    char* r = p;
    p += (bytes + 255) & ~(size_t)255;
    return r;
  };
  const size_t NB = 8, N = 2048, CIN = 512, CO = 512;
  _Float16* Wb = (_Float16*)alloc(1024 * 512 * sizeof(_Float16));
  _Float16* xT = (_Float16*)alloc(NB * N * CIN * sizeof(_Float16));
  _Float16* qkT = (_Float16*)alloc(NB * N * 512 * sizeof(_Float16));  // [n][q|k]
  _Float16* v = (_Float16*)alloc(NB * CO * N * sizeof(_Float16));     // [c][n]
  size_t base_used = (size_t)(p - (char*)d_ws);

  // per-batch bytes for the sim chain: fp16 P + partials + scale + slack
  const size_t per_b =
      (size_t)N * N * 2 + 2 * 32 * N * 4 + 32 * N * 2 + 8192;
  int cb = 8;
  while (cb > 1 && base_used + (size_t)cb * per_b > ws_size) cb >>= 1;
  _Float16* simH = (_Float16*)alloc((size_t)cb * N * N * 2);
  float* pm = (float*)alloc((size_t)cb * 32 * N * 4);
  float* ps = (float*)alloc((size_t)cb * 32 * N * 4);
  _Float16* scl = (_Float16*)alloc((size_t)cb * 32 * N * 2);

  // 1) weight convert + x transpose-convert
  conv_w<<<dim3(1024 * 512 / 256), 256, 0, stream>>>(Wq, Wk, Wv, Wb);
  conv_xT<<<dim3(64, 16, 8), 256, 0, stream>>>(x, xT);

  // 2) merged projections (q,k,v in one pass over xT):
  //    rows<512 -> qkT[n][o] transposed; rows>=512 -> v[c][n] natural
  gemm_nt<_Float16, 3, 1><<<dim3(16, 8, 8), 256, 0, stream>>>(
      Wb, xT, qkT, v, 512, 512, 512, 512, 2048, 0, (long)(N * CIN),
      (long)(N * 512), nullptr, nullptr);

  // 3) per-chunk: simH = fp16(exp(qT.kT^T - mx_wave)) + partials; merge ->
  //    fp16 scale; stage-D GEMM applies scale during A-staging -> out
  for (int b0 = 0; b0 < 8; b0 += cb) {
    const _Float16* qT = qkT + (size_t)b0 * N * 512;        // [m][c], lda 512
    const _Float16* kT = qkT + (size_t)b0 * N * 512 + 256;  // [k][c], ldb 512
    gemm_nt<_Float16, 2, 2><<<dim3(16, 16, cb), 256, 0, stream>>>(
        qT, kT, simH, nullptr, 256, 512, 512, 2048, 0, (long)(N * 512),
        (long)(N * 512), (long)(N * N), pm, ps);
    colstats2<<<dim3(cb * 8), 256, 0, stream>>>(pm, ps, scl);
    gemm_av<<<dim3(32 * cb), 512, 0, stream>>>(
        simH, v + (size_t)b0 * CO * N, scl, out + (size_t)b0 * N * CO, cb);
  }
}

// Round 6
// 198.475 us; speedup vs baseline: 1.2020x; 1.0874x over previous
//
#include <hip/hip_runtime.h>

typedef _Float16 half8 __attribute__((ext_vector_type(8)));
typedef _Float16 half4v __attribute__((ext_vector_type(4)));
typedef _Float16 half2v __attribute__((ext_vector_type(2)));
typedef float f32x4 __attribute__((ext_vector_type(4)));

// async 16B global->LDS copy (HW: LDS dest = wave-uniform base + lane*16)
#define ASYNC_CP16(gp, lp)                                       \
  __builtin_amdgcn_global_load_lds(                              \
      (const __attribute__((address_space(1))) void*)(gp),       \
      (__attribute__((address_space(3))) void*)(lp), 16, 0, 0)

static __device__ __forceinline__ half8 mulw(half8 a, half8 s) {
  half8 o;
#pragma unroll
  for (int j = 0; j < 8; j++) o[j] = a[j] * s[j];  // v_pk_mul_f16 x4
  return o;
}

// ---------------------------------------------------------------------------
// Convert Wq||Wk||Wv (fp32 [O,512] each) -> Wb fp16 [1024][512] (c-inner)
// ---------------------------------------------------------------------------
__global__ __launch_bounds__(256) void conv_w(const float* __restrict__ Wq,
                                              const float* __restrict__ Wk,
                                              const float* __restrict__ Wv,
                                              _Float16* __restrict__ Wb) {
  int idx = blockIdx.x * 256 + threadIdx.x;  // 0 .. 1024*512
  int row = idx >> 9;
  float v;
  if (row < 256)      v = Wq[idx];
  else if (row < 512) v = Wk[idx - 256 * 512];
  else                v = Wv[idx - 512 * 512];
  Wb[idx] = (_Float16)v;
}

// ---------------------------------------------------------------------------
// x fp32 [B][512][2048] -> xT fp16 [B][2048][512]   (LDS-tiled transpose)
// ---------------------------------------------------------------------------
__global__ __launch_bounds__(256) void conv_xT(const float* __restrict__ x,
                                               _Float16* __restrict__ xT) {
  __shared__ float T[32][33];
  const int b = blockIdx.z;
  const int n0 = blockIdx.x * 32, c0 = blockIdx.y * 32;
  const int t = threadIdx.x;
  const float* xb = x + (size_t)b * 512 * 2048;
  const int n2 = t & 15, cr = t >> 4;  // load: 16 float2-cols x 16 c-rows
#pragma unroll
  for (int r = 0; r < 2; r++) {
    int c = cr + r * 16;
    float2 v = *(const float2*)&xb[(size_t)(c0 + c) * 2048 + n0 + n2 * 2];
    T[c][n2 * 2] = v.x;
    T[c][n2 * 2 + 1] = v.y;
  }
  __syncthreads();
  _Float16* xtb = xT + (size_t)b * 2048 * 512;
  const int c2 = t & 15, nr = t >> 4;  // store: 16 half2-cols x 16 n-rows
#pragma unroll
  for (int r = 0; r < 2; r++) {
    int n = nr + r * 16;
    half2v h;
    h[0] = (_Float16)T[c2 * 2][n];
    h[1] = (_Float16)T[c2 * 2 + 1][n];
    *(half2v*)&xtb[(size_t)(n0 + n) * 512 + c0 + c2 * 2] = h;
  }
}

// ---------------------------------------------------------------------------
// NT-GEMM (proj + sim): C[m][n] = sum_k A[m][k]*B[n][k], fp16 in.
// Block 256 thr = 4 waves; block tile 128x128; wave tile 64x64 (4x4 MFMAs).
// BUFS-buffered async staging (global_load_lds w=16), prefetch dist BUFS-1,
// raw-asm barrier (vmcnt(4) mid-loop for BUFS=3; in-order vmcnt retire).
// XOR swizzle on the GLOBAL source side keeps frag ds_read_b128 conflict-free:
//   LDS slot (row r, 16B-chunk c') holds global chunk c' ^ ((r>>1)&3).
// MODE 1 (PROJ3): m_blk<512 -> transposed fp16 store into C (qkT); else
//   natural fp16 store into C2 (v) at row m-512.
// MODE 2 (SIM): store h = fp16(exp(logit - mx)) where mx is the PER-WAVE
//   column max over its 64 m's; emit partials pm=mx, ps=sum(rounded h) at
//   64-row granularity: pm/ps[b][32][2048].  (no cross-wave merge needed)
// ---------------------------------------------------------------------------
template <typename OutT, int BUFS, int MODE>
__global__ __launch_bounds__(256) void gemm_nt(
    const _Float16* __restrict__ A, const _Float16* __restrict__ B,
    OutT* __restrict__ C, OutT* __restrict__ C2, int K, int lda, int ldb,
    int ldc, int ldc2, long sA, long sB, long sC, float* __restrict__ pm,
    float* __restrict__ ps) {
  A += (size_t)blockIdx.z * sA;
  B += (size_t)blockIdx.z * sB;
  C += (size_t)blockIdx.z * sC;
  if constexpr (MODE == 1) C2 += (size_t)blockIdx.z * sC;
  const int m_blk = blockIdx.y * 128, n_blk = blockIdx.x * 128;

  __shared__ __align__(16) _Float16 As[BUFS][4096];  // [buf][128 rows][32 k]
  __shared__ __align__(16) _Float16 Bs[BUFS][4096];

  const int t = threadIdx.x;
  const int lane = t & 63, wave = t >> 6;
  const int quad = lane >> 4, l16 = lane & 15;
  const int wm = (wave & 1) * 64, wn = (wave >> 1) * 64;

  const int srow = 16 * wave + (lane >> 2);
  const int schunk = (lane & 3) ^ ((lane >> 3) & 3);  // XOR swizzle
  const _Float16* gA0 = A + (size_t)(m_blk + srow) * lda + schunk * 8;
  const _Float16* gA1 = gA0 + (size_t)64 * lda;
  const _Float16* gB0 = B + (size_t)(n_blk + srow) * ldb + schunk * 8;
  const _Float16* gB1 = gB0 + (size_t)64 * ldb;
  const int lofs = wave * 512 + lane * 8;  // halves within one buffer

  const int rchunk = (quad ^ ((l16 >> 1) & 3)) * 8;

  f32x4 acc[4][4] = {};

#pragma unroll
  for (int pb = 0; pb < BUFS - 1; pb++) {
    if (pb * 32 < K) {
      ASYNC_CP16(gA0 + pb * 32, &As[pb][lofs]);
      ASYNC_CP16(gA1 + pb * 32, &As[pb][lofs + 2048]);
      ASYNC_CP16(gB0 + pb * 32, &Bs[pb][lofs]);
      ASYNC_CP16(gB1 + pb * 32, &Bs[pb][lofs + 2048]);
    }
  }

  int ib = 0;
  for (int k0 = 0; k0 < K; k0 += 32) {
    if constexpr (BUFS == 3) {
      if (k0 + 32 < K)
        asm volatile("s_waitcnt vmcnt(4)\n\ts_barrier" ::: "memory");
      else
        asm volatile("s_waitcnt vmcnt(0)\n\ts_barrier" ::: "memory");
    } else {
      asm volatile("s_waitcnt vmcnt(0)\n\ts_barrier" ::: "memory");
    }
    if (k0 + (BUFS - 1) * 32 < K) {
      int nb = ib + BUFS - 1;
      if (nb >= BUFS) nb -= BUFS;
      const int ko = k0 + (BUFS - 1) * 32;
      ASYNC_CP16(gA0 + ko, &As[nb][lofs]);
      ASYNC_CP16(gA1 + ko, &As[nb][lofs + 2048]);
      ASYNC_CP16(gB0 + ko, &Bs[nb][lofs]);
      ASYNC_CP16(gB1 + ko, &Bs[nb][lofs + 2048]);
    }
    half8 af[4], bf[4];
#pragma unroll
    for (int i = 0; i < 4; i++) {
      af[i] = *(const half8*)&As[ib][(wm + i * 16 + l16) * 32 + rchunk];
      bf[i] = *(const half8*)&Bs[ib][(wn + i * 16 + l16) * 32 + rchunk];
    }
#pragma unroll
    for (int i = 0; i < 4; i++)
#pragma unroll
      for (int j = 0; j < 4; j++)
        acc[i][j] =
            __builtin_amdgcn_mfma_f32_16x16x32_f16(af[i], bf[j], acc[i][j], 0, 0, 0);
    ib++;
    if (ib == BUFS) ib = 0;
  }

  if constexpr (MODE == 2) {
    // per-wave-column softmax partials + exp-store (D row = quad*4+reg,
    // col = l16 in each 16x16 tile; wave column has 64 m's across i,quad,r)
#pragma unroll
    for (int j = 0; j < 4; j++) {
      const int n0 = n_blk + wn + j * 16 + l16;
      float mx = acc[0][j][0];
#pragma unroll
      for (int i = 0; i < 4; i++)
#pragma unroll
        for (int r = 0; r < 4; r++) mx = fmaxf(mx, acc[i][j][r]);
      mx = fmaxf(mx, __shfl_xor(mx, 16, 64));
      mx = fmaxf(mx, __shfl_xor(mx, 32, 64));
      float es = 0.f;
#pragma unroll
      for (int i = 0; i < 4; i++) {
        const int m0 = m_blk + wm + i * 16 + quad * 4;
#pragma unroll
        for (int r = 0; r < 4; r++) {
          _Float16 h = (_Float16)__expf(acc[i][j][r] - mx);
          C[(size_t)(m0 + r) * ldc + n0] = h;
          es += (float)h;
        }
      }
      es += __shfl_xor(es, 16, 64);
      es += __shfl_xor(es, 32, 64);
      if (quad == 0) {
        size_t o =
            ((size_t)blockIdx.z * 32 + blockIdx.y * 2 + (wave & 1)) * 2048 + n0;
        pm[o] = mx;
        ps[o] = es;
      }
    }
  } else {
#pragma unroll
    for (int i = 0; i < 4; i++) {
      const int m0 = m_blk + wm + i * 16 + quad * 4;
#pragma unroll
      for (int j = 0; j < 4; j++) {
        const int n0 = n_blk + wn + j * 16 + l16;
        if constexpr (MODE == 1) {
          if (m_blk < 512) {  // q|k rows: transposed store into qkT
            half4v h;
#pragma unroll
            for (int r = 0; r < 4; r++) h[r] = (_Float16)acc[i][j][r];
            *(half4v*)&C[(size_t)n0 * ldc + m0] = h;
          } else {  // v rows: natural store v[(m-512)][n]
#pragma unroll
            for (int r = 0; r < 4; r++)
              C2[(size_t)(m0 - 512 + r) * ldc2 + n0] = (OutT)acc[i][j][r];
          }
        } else {
#pragma unroll
          for (int r = 0; r < 4; r++)
            C[(size_t)(m0 + r) * ldc + n0] = (OutT)acc[i][j][r];
        }
      }
    }
  }
}

// ---------------------------------------------------------------------------
// Merge 32 per-64-row partials per column -> fp16 scale[b][32][2048]:
// scale[i][col] = exp(pm_i - M) / S,  S = sum_i ps_i * exp(pm_i - M).
// attn[m,k] = h[m,k] * scale[m>>6, k]; normalization exact by construction.
// Grid (nb*2048/256).
// ---------------------------------------------------------------------------
__global__ __launch_bounds__(256) void colstats2(const float* __restrict__ pm,
                                                 const float* __restrict__ ps,
                                                 _Float16* __restrict__ scl) {
  const int idx = blockIdx.x * 256 + threadIdx.x;  // b*2048 + col
  const int b = idx >> 11, col = idx & 2047;
  const float* pmb = pm + (size_t)b * 32 * 2048 + col;
  const float* psb = ps + (size_t)b * 32 * 2048 + col;
  float pv[32];
  float m = -3.0e38f;
#pragma unroll
  for (int i = 0; i < 32; i++) {
    pv[i] = pmb[(size_t)i * 2048];
    m = fmaxf(m, pv[i]);
  }
  float s = 0.f;
#pragma unroll
  for (int i = 0; i < 32; i++) {
    pv[i] = __expf(pv[i] - m);
    s += psb[(size_t)i * 2048] * pv[i];
  }
  const float inv = 1.0f / s;
  _Float16* so = scl + (size_t)b * 32 * 2048 + col;
#pragma unroll
  for (int i = 0; i < 32; i++) so[(size_t)i * 2048] = (_Float16)(pv[i] * inv);
}

// ---------------------------------------------------------------------------
// Stage-D: out[m][c] = sum_k (P[m][k]*scale[m>>6,k]) * V[c][k].
// P fp16 [2048][2048] (unnorm. exp), V fp16 [512][2048], scale fp16 [32][2048]
// per batch, out fp32 [2048][512].
// ROUND-6: phase-split schedule (T3+T4+T5 port).  Evidence: R0/R1/R2/R3/R5
//   all land at ~2400 cyc per K32 per SIMD with MfmaUtil pinned ~20%;
//   component sum MFMA(620)+LDS(1000)+VALU(260)+waits == 2400 -> the
//   2-phase barrier loop SERIALIZES the pipes (guide m233).  Occupancy
//   (R1), operand placement (R2), no-barrier (R3), cache traffic (R5) all
//   eliminated.  Fix = m201/m218 regime: per-BK64 tile, 2 sub-phases of
//   {ds_read subtile -> issue stage -> barrier -> setprio MFMA setprio ->
//   barrier}, counted vmcnt(4) once per K-tile (A-glob prefetches stay in
//   flight across barriers, never drained mid-loop).
// Geometry (= R5, the proven 8-wave quadrant): 512 thr, tile 128m x 256c,
//   wave 64x64 (4x4), grid 32/batch x 8 = 256 = 1 block/CU, batch-per-XCD.
// LDS: As[2][2][128x32], Bs[2][2][256x32] (buf, kkblk; 64-B rows keep the
//   proven conflict-free XOR swizzle bank math) = 96 KB.
// B staging: 4 cp16/thread/K-tile, all issued in phase 0 (oldest in vmcnt
//   queue).  Stage s: kkblk=s>>1, rows (s&1)*128 + wave*16 + (lane>>2).
// A staging: reg+mulw(scale)+ds_write, glob prefetch dist 2 K-tiles issued
//   in phase 1; per K-tile 2 writes (kkblk 0 in ph0, 1 in ph1).
// vmcnt(4) at phase-1 wait: outstanding = [cp x4 (oldest), glob x4] ->
//   retires cps (buf n readable after barrier), keeps globs in flight.
//   T==30: globs skipped -> vmcnt(0).  lgkmcnt(0) flushes ds_writes.
// ---------------------------------------------------------------------------
__global__ __launch_bounds__(512) void gemm_av(const _Float16* __restrict__ P,
                                               const _Float16* __restrict__ V,
                                               const _Float16* __restrict__ scl,
                                               float* __restrict__ C,
                                               int cbatch) {
  int lin = blockIdx.x, z, idx;
  if (cbatch == 8) {
    z = lin & 7;      // batch = XCD
    idx = lin >> 3;   // 0..31
  } else {
    z = lin >> 5;
    idx = lin & 31;
  }
  const int n_blk = (idx & 1) * 256;   // c-dim (2 blocks)
  const int m_blk = (idx >> 1) * 128;  // m-dim (16 blocks)
  P += (size_t)z * 2048 * 2048;
  V += (size_t)z * 512 * 2048;
  scl += (size_t)z * 32 * 2048;
  C += (size_t)z * 2048 * 512;

  __shared__ __align__(16) _Float16 As[2][2][4096];  // [buf][kk][128r x 32k]
  __shared__ __align__(16) _Float16 Bs[2][2][8192];  // [buf][kk][256r x 32k]

  const int t = threadIdx.x;
  const int lane = t & 63, wave = t >> 6;
  const int quad = lane >> 4, l16 = lane & 15;
  const int wm = (wave & 1) * 64, wn = (wave >> 1) * 64;

  // A staging: thread t -> row t>>2, slot chunk t&3, swizzled data chunk
  const int arow = t >> 2;                       // 0..127
  const int aslot = t & 3;
  const int adc = aslot ^ ((arow >> 1) & 3);     // global-side XOR swizzle
  const _Float16* gA = P + (size_t)(m_blk + arow) * 2048 + adc * 8;
  const _Float16* gS = scl + (size_t)((m_blk + arow) >> 6) * 2048 + adc * 8;
  const int awofs = arow * 32 + aslot * 8;

  // B staging (cp16): per wave-instruction 16 rows x 64 B; sigma(row) is
  // rhalf-invariant ((r>>1)&3 with r = rhalf*128 + brow0, 128/2 % 4 == 0)
  const int brow0 = (wave << 4) + (lane >> 2);          // 0..127
  const int bdc = (lane & 3) ^ ((brow0 >> 1) & 3);
  const _Float16* gB = V + (size_t)(n_blk + brow0) * 2048 + bdc * 8;
  const int bwofs = wave << 9;  // wave*512 halves (HW adds lane*16B)

  const int rchunk = (quad ^ ((l16 >> 1) & 3)) * 8;

  f32x4 acc[4][4] = {};

  // ---- prologue: B tile0 (4 cp16); A tile0 staged; A tile1 in regs ----
  ASYNC_CP16(gB, &Bs[0][0][bwofs]);
  ASYNC_CP16(gB + (size_t)128 * 2048, &Bs[0][0][4096 + bwofs]);
  ASYNC_CP16(gB + 32, &Bs[0][1][bwofs]);
  ASYNC_CP16(gB + (size_t)128 * 2048 + 32, &Bs[0][1][4096 + bwofs]);
  {
    half8 a00 = *(const half8*)(gA);
    half8 s00 = *(const half8*)(gS);
    half8 a01 = *(const half8*)(gA + 32);
    half8 s01 = *(const half8*)(gS + 32);
    *(half8*)&As[0][0][awofs] = mulw(a00, s00);
    *(half8*)&As[0][1][awofs] = mulw(a01, s01);
  }
  half8 pA0 = *(const half8*)(gA + 64);
  half8 pS0 = *(const half8*)(gS + 64);
  half8 pA1 = *(const half8*)(gA + 96);
  half8 pS1 = *(const half8*)(gS + 96);
  asm volatile("s_waitcnt vmcnt(4) lgkmcnt(0)\n\ts_barrier" ::: "memory");
  __builtin_amdgcn_sched_barrier(0);

  for (int T = 0; T < 32; T++) {
    const int c = T & 1, n = c ^ 1;
    const int k1 = (T + 1) * 64;  // B stage k-base
    const int k2 = (T + 2) * 64;  // A glob prefetch k-base
    // ---------------- phase 0 ----------------
    half8 af[4], bf[4];
#pragma unroll
    for (int i = 0; i < 4; i++) {
      af[i] = *(const half8*)&As[c][0][(wm + i * 16 + l16) * 32 + rchunk];
      bf[i] = *(const half8*)&Bs[c][0][(wn + i * 16 + l16) * 32 + rchunk];
    }
    if (T < 31) {  // all 4 B cp16 (oldest in vmcnt queue) + A kk0 write
      ASYNC_CP16(gB + k1, &Bs[n][0][bwofs]);
      ASYNC_CP16(gB + (size_t)128 * 2048 + k1, &Bs[n][0][4096 + bwofs]);
      ASYNC_CP16(gB + k1 + 32, &Bs[n][1][bwofs]);
      ASYNC_CP16(gB + (size_t)128 * 2048 + k1 + 32, &Bs[n][1][4096 + bwofs]);
      *(half8*)&As[n][0][awofs] = mulw(pA0, pS0);
    }
    asm volatile("s_barrier" ::: "memory");
    __builtin_amdgcn_sched_barrier(0);
    __builtin_amdgcn_s_setprio(1);
#pragma unroll
    for (int i = 0; i < 4; i++)
#pragma unroll
      for (int j = 0; j < 4; j++)
        acc[i][j] =
            __builtin_amdgcn_mfma_f32_16x16x32_f16(af[i], bf[j], acc[i][j], 0, 0, 0);
    __builtin_amdgcn_s_setprio(0);
    asm volatile("s_barrier" ::: "memory");
    __builtin_amdgcn_sched_barrier(0);
    // ---------------- phase 1 ----------------
    half8 af2[4], bf2[4];
#pragma unroll
    for (int i = 0; i < 4; i++) {
      af2[i] = *(const half8*)&As[c][1][(wm + i * 16 + l16) * 32 + rchunk];
      bf2[i] = *(const half8*)&Bs[c][1][(wn + i * 16 + l16) * 32 + rchunk];
    }
    half8 fA0, fS0, fA1, fS1;
    if (T < 30) {  // A glob prefetch for T+2 (stays in flight across barrier)
      fA0 = *(const half8*)(gA + k2);
      fS0 = *(const half8*)(gS + k2);
      fA1 = *(const half8*)(gA + k2 + 32);
      fS1 = *(const half8*)(gS + k2 + 32);
    }
    if (T < 31) *(half8*)&As[n][1][awofs] = mulw(pA1, pS1);
    if (T < 30) {
      pA0 = fA0;
      pS0 = fS0;
      pA1 = fA1;
      pS1 = fS1;
    }
    if (T < 30)
      asm volatile("s_waitcnt vmcnt(4) lgkmcnt(0)\n\ts_barrier" ::: "memory");
    else
      asm volatile("s_waitcnt vmcnt(0) lgkmcnt(0)\n\ts_barrier" ::: "memory");
    __builtin_amdgcn_sched_barrier(0);
    __builtin_amdgcn_s_setprio(1);
#pragma unroll
    for (int i = 0; i < 4; i++)
#pragma unroll
      for (int j = 0; j < 4; j++)
        acc[i][j] =
            __builtin_amdgcn_mfma_f32_16x16x32_f16(af2[i], bf2[j], acc[i][j], 0, 0, 0);
    __builtin_amdgcn_s_setprio(0);
    asm volatile("s_barrier" ::: "memory");
    __builtin_amdgcn_sched_barrier(0);
  }

  // epilogue: natural fp32 store C[m][c]
#pragma unroll
  for (int i = 0; i < 4; i++) {
    const int m0 = m_blk + wm + i * 16 + quad * 4;
#pragma unroll
    for (int j = 0; j < 4; j++) {
      const int n0 = n_blk + wn + j * 16 + l16;
#pragma unroll
      for (int r = 0; r < 4; r++) C[(size_t)(m0 + r) * 512 + n0] = acc[i][j][r];
    }
  }
}

// ---------------------------------------------------------------------------
extern "C" void kernel_launch(void* const* d_in, const int* in_sizes, int n_in,
                              void* d_out, int out_size, void* d_ws,
                              size_t ws_size, hipStream_t stream) {
  const float* x = (const float*)d_in[0];
  const float* Wq = (const float*)d_in[1];
  const float* Wk = (const float*)d_in[2];
  const float* Wv = (const float*)d_in[3];
  float* out = (float*)d_out;

  char* p = (char*)d_ws;
  auto alloc = [&](size_t bytes) -> char* {
    char* r = p;
    p += (bytes + 255) & ~(size_t)255;
    return r;
  };
  const size_t NB = 8, N = 2048, CIN = 512, CO = 512;
  _Float16* Wb = (_Float16*)alloc(1024 * 512 * sizeof(_Float16));
  _Float16* xT = (_Float16*)alloc(NB * N * CIN * sizeof(_Float16));
  _Float16* qkT = (_Float16*)alloc(NB * N * 512 * sizeof(_Float16));  // [n][q|k]
  _Float16* v = (_Float16*)alloc(NB * CO * N * sizeof(_Float16));     // [c][n]
  size_t base_used = (size_t)(p - (char*)d_ws);

  // per-batch bytes for the sim chain: fp16 P + partials + scale + slack
  const size_t per_b =
      (size_t)N * N * 2 + 2 * 32 * N * 4 + 32 * N * 2 + 8192;
  int cb = 8;
  while (cb > 1 && base_used + (size_t)cb * per_b > ws_size) cb >>= 1;
  _Float16* simH = (_Float16*)alloc((size_t)cb * N * N * 2);
  float* pm = (float*)alloc((size_t)cb * 32 * N * 4);
  float* ps = (float*)alloc((size_t)cb * 32 * N * 4);
  _Float16* scl = (_Float16*)alloc((size_t)cb * 32 * N * 2);

  // 1) weight convert + x transpose-convert
  conv_w<<<dim3(1024 * 512 / 256), 256, 0, stream>>>(Wq, Wk, Wv, Wb);
  conv_xT<<<dim3(64, 16, 8), 256, 0, stream>>>(x, xT);

  // 2) merged projections (q,k,v in one pass over xT):
  //    rows<512 -> qkT[n][o] transposed; rows>=512 -> v[c][n] natural
  gemm_nt<_Float16, 3, 1><<<dim3(16, 8, 8), 256, 0, stream>>>(
      Wb, xT, qkT, v, 512, 512, 512, 512, 2048, 0, (long)(N * CIN),
      (long)(N * 512), nullptr, nullptr);

  // 3) per-chunk: simH = fp16(exp(qT.kT^T - mx_wave)) + partials; merge ->
  //    fp16 scale; stage-D GEMM applies scale during A-staging -> out
  for (int b0 = 0; b0 < 8; b0 += cb) {
    const _Float16* qT = qkT + (size_t)b0 * N * 512;        // [m][c], lda 512
    const _Float16* kT = qkT + (size_t)b0 * N * 512 + 256;  // [k][c], ldb 512
    gemm_nt<_Float16, 2, 2><<<dim3(16, 16, cb), 256, 0, stream>>>(
        qT, kT, simH, nullptr, 256, 512, 512, 2048, 0, (long)(N * 512),
        (long)(N * 512), (long)(N * N), pm, ps);
    colstats2<<<dim3(cb * 8), 256, 0, stream>>>(pm, ps, scl);
    gemm_av<<<dim3(32 * cb), 512, 0, stream>>>(
        simH, v + (size_t)b0 * CO * N, scl, out + (size_t)b0 * N * CO, cb);
  }
}